// Round 3
// 426.660 us; speedup vs baseline: 1.0778x; 1.0778x over previous
//
#include <hip/hip_runtime.h>

static constexpr int nL = 103, nR = 512, nB = 2, nS = 512, nD = 768;
static constexpr float INV_SQRT_D = 0.03608439182435161f; // 1/sqrt(768)

typedef short bf16x8 __attribute__((ext_vector_type(8)));
typedef float f32x4 __attribute__((ext_vector_type(4)));
typedef unsigned short u16;
typedef unsigned short ushort4v __attribute__((ext_vector_type(4)));
typedef unsigned short ushort8v __attribute__((ext_vector_type(8)));

// ws layout (float offsets). Total ~4.16 MiB.
static constexpr size_t OFF_OUTB = 0;                  // 1024x768 bf16 = 393216 fl
static constexpr size_t OFF_MBF  = 393216;             // 768x768 bf16 = 294912 fl
static constexpr size_t OFF_KQB  = 688128;             // 96*1024*8 u16 = 393216 fl
static constexpr size_t OFF_QBK  = 1081344;            // 768 : Wq@bk
static constexpr size_t OFF_WKBQ = OFF_QBK + 768;      // 768 : Wk@bq
static constexpr size_t OFF_WV3  = OFF_WKBQ + 768;     // 3*768 : Wv@{wld,wad,wtd}
static constexpr size_t OFF_CST  = OFF_WV3 + 2304;     // 4
static constexpr size_t OFF_C    = OFF_CST + 4;        // 1024
static constexpr size_t OFF_HV   = OFF_C + 1024;       // 3*1024
static constexpr size_t OFF_SUM  = OFF_HV + 3072;      // 3*nB*nL = 618

__device__ inline float wredsum(float v) {
#pragma unroll
  for (int o = 32; o; o >>= 1) v += __shfl_xor(v, o);
  return v;
}

__device__ inline u16 f2bf(float f) {  // RNE fp32 -> bf16
  unsigned u = __builtin_bit_cast(unsigned, f);
  u += 0x7FFFu + ((u >> 16) & 1u);
  return (u16)(u >> 16);
}

__device__ inline bf16x8 cvt8(float4 a, float4 b) {
  ushort8v u;
  u[0]=f2bf(a.x); u[1]=f2bf(a.y); u[2]=f2bf(a.z); u[3]=f2bf(a.w);
  u[4]=f2bf(b.x); u[5]=f2bf(b.y); u[6]=f2bf(b.z); u[7]=f2bf(b.w);
  return __builtin_bit_cast(bf16x8, u);
}

// ---- K0: row-dots + consts + zero SUM + pack outp->bf16 --------------------
__global__ __launch_bounds__(256) void k_prep(
    const float* __restrict__ Wq, const float* __restrict__ Wk,
    const float* __restrict__ Wv, const float* __restrict__ bq,
    const float* __restrict__ bk, const float* __restrict__ bv,
    const float* __restrict__ wld, const float* __restrict__ wad,
    const float* __restrict__ wtd, const float* __restrict__ outp,
    float* __restrict__ ws) {
  int tid = threadIdx.x, lane = tid & 63, w = tid >> 6;
  int bid = blockIdx.x;
  if (bid < 192) {
    int row = bid * 4 + w;
    const float* wqr = Wq + (size_t)row * nD;
    const float* wkr = Wk + (size_t)row * nD;
    const float* wvr = Wv + (size_t)row * nD;
    float dq = 0.f, dk = 0.f, d0 = 0.f, d1 = 0.f, d2 = 0.f;
#pragma unroll
    for (int k = 0; k < 3; ++k) {
      int off = lane * 4 + k * 256;
      float4 q4 = *(const float4*)(wqr + off);
      float4 k4 = *(const float4*)(wkr + off);
      float4 v4 = *(const float4*)(wvr + off);
      float4 bk4 = *(const float4*)(bk + off);
      float4 bq4 = *(const float4*)(bq + off);
      float4 l4 = *(const float4*)(wld + off);
      float4 a4 = *(const float4*)(wad + off);
      float4 t4 = *(const float4*)(wtd + off);
      dq += q4.x*bk4.x + q4.y*bk4.y + q4.z*bk4.z + q4.w*bk4.w;
      dk += k4.x*bq4.x + k4.y*bq4.y + k4.z*bq4.z + k4.w*bq4.w;
      d0 += v4.x*l4.x + v4.y*l4.y + v4.z*l4.z + v4.w*l4.w;
      d1 += v4.x*a4.x + v4.y*a4.y + v4.z*a4.z + v4.w*a4.w;
      d2 += v4.x*t4.x + v4.y*t4.y + v4.z*t4.z + v4.w*t4.w;
    }
    dq = wredsum(dq); dk = wredsum(dk);
    d0 = wredsum(d0); d1 = wredsum(d1); d2 = wredsum(d2);
    if (lane == 0) {
      ws[OFF_QBK + row] = dq;
      ws[OFF_WKBQ + row] = dk;
      ws[OFF_WV3 + row] = d0;
      ws[OFF_WV3 + 768 + row] = d1;
      ws[OFF_WV3 + 1536 + row] = d2;
    }
  } else if (bid == 192) {
    if (tid < 64) {
      float c0 = 0.f, c1 = 0.f, c2 = 0.f, c3 = 0.f;
      for (int j = lane; j < nD; j += 64) {
        c0 += bq[j]*bk[j]; c1 += bv[j]*wld[j]; c2 += bv[j]*wad[j]; c3 += bv[j]*wtd[j];
      }
      c0 = wredsum(c0); c1 = wredsum(c1); c2 = wredsum(c2); c3 = wredsum(c3);
      if (lane == 0) {
        ws[OFF_CST+0] = c0; ws[OFF_CST+1] = c1; ws[OFF_CST+2] = c2; ws[OFF_CST+3] = c3;
      }
    }
    for (int i = tid; i < 3 * nB * nL; i += 256) ws[OFF_SUM + i] = 0.f;
  } else {
    // pack outp -> outb bf16: blocks 193..384, 4096 fl per block
    u16* outb = (u16*)(ws + OFF_OUTB);
    size_t e = ((size_t)(bid - 193) * 256 + tid) * 16;
    float4 f0 = *(const float4*)(outp + e);
    float4 f1 = *(const float4*)(outp + e + 4);
    float4 f2 = *(const float4*)(outp + e + 8);
    float4 f3 = *(const float4*)(outp + e + 12);
    *(ushort8v*)(outb + e)     = __builtin_bit_cast(ushort8v, cvt8(f0, f1));
    *(ushort8v*)(outb + e + 8) = __builtin_bit_cast(ushort8v, cvt8(f2, f3));
  }
}

// ---- K1: M = Wq @ Wk^T (direct-fragment MFMA, no LDS) + fused k_chv --------
__global__ __launch_bounds__(256) void k_mmM_chv(
    const float* __restrict__ Wq, const float* __restrict__ Wk,
    const float* __restrict__ outp, float* __restrict__ ws) {
  int tid = threadIdx.x, lane = tid & 63, w = tid >> 6;
  int bid = blockIdx.x;
  if (bid < 144) {
    u16* Mbf = (u16*)(ws + OFF_MBF);
    const int ti = bid / 12, tj = bid % 12;
    const int c4 = lane & 15, q4 = lane >> 4, wr = w >> 1, wc = w & 1;
    f32x4 acc[2][2];
#pragma unroll
    for (int i = 0; i < 2; ++i)
#pragma unroll
      for (int j = 0; j < 2; ++j) acc[i][j] = (f32x4){0.f,0.f,0.f,0.f};
    const float* Ab[2]; const float* Bb[2];
#pragma unroll
    for (int i = 0; i < 2; ++i)
      Ab[i] = Wq + (size_t)(ti*64 + wr*32 + i*16 + c4) * nD + q4*8;
#pragma unroll
    for (int j = 0; j < 2; ++j)
      Bb[j] = Wk + (size_t)(tj*64 + wc*32 + j*16 + c4) * nD + q4*8;
    for (int kt = 0; kt < 24; ++kt) {
      bf16x8 af[2], bf[2];
#pragma unroll
      for (int i = 0; i < 2; ++i)
        af[i] = cvt8(*(const float4*)(Ab[i] + kt*32), *(const float4*)(Ab[i] + kt*32 + 4));
#pragma unroll
      for (int j = 0; j < 2; ++j)
        bf[j] = cvt8(*(const float4*)(Bb[j] + kt*32), *(const float4*)(Bb[j] + kt*32 + 4));
#pragma unroll
      for (int i = 0; i < 2; ++i)
#pragma unroll
        for (int j = 0; j < 2; ++j)
          acc[i][j] = __builtin_amdgcn_mfma_f32_16x16x32_bf16(af[i], bf[j], acc[i][j], 0, 0, 0);
    }
#pragma unroll
    for (int i = 0; i < 2; ++i)
#pragma unroll
      for (int j = 0; j < 2; ++j) {
        int n = tj*64 + wc*32 + j*16 + c4;
#pragma unroll
        for (int reg = 0; reg < 4; ++reg) {
          int m = ti*64 + wr*32 + i*16 + q4*4 + reg;
          Mbf[(size_t)m * nD + n] = f2bf(acc[i][j][reg]);
        }
      }
  } else {
    // chv: wave per (b,s) row
    int idx = (bid - 144) * 4 + w;
    const float* row = outp + (size_t)idx * nD;
    const float* wkbq = ws + OFF_WKBQ;
    const float* wv0 = ws + OFF_WV3;
    const float* wv1 = ws + OFF_WV3 + 768;
    const float* wv2 = ws + OFF_WV3 + 1536;
    float a0 = 0.f, a1 = 0.f, a2 = 0.f, a3 = 0.f;
#pragma unroll
    for (int k = 0; k < 3; ++k) {
      int off = lane * 4 + k * 256;
      float4 o4 = *(const float4*)(row + off);
      float4 k4 = *(const float4*)(wkbq + off);
      float4 l4 = *(const float4*)(wv0 + off);
      float4 c4v = *(const float4*)(wv1 + off);
      float4 t4 = *(const float4*)(wv2 + off);
      a0 += o4.x*k4.x + o4.y*k4.y + o4.z*k4.z + o4.w*k4.w;
      a1 += o4.x*l4.x + o4.y*l4.y + o4.z*l4.z + o4.w*l4.w;
      a2 += o4.x*c4v.x + o4.y*c4v.y + o4.z*c4v.z + o4.w*c4v.w;
      a3 += o4.x*t4.x + o4.y*t4.y + o4.z*t4.z + o4.w*t4.w;
    }
    a0 = wredsum(a0); a1 = wredsum(a1); a2 = wredsum(a2); a3 = wredsum(a3);
    if (lane == 0) {
      ws[OFF_C + idx]         = a0 + ws[OFF_CST+0];
      ws[OFF_HV + idx]        = a1 + ws[OFF_CST+1];
      ws[OFF_HV + 1024 + idx] = a2 + ws[OFF_CST+2];
      ws[OFF_HV + 2048 + idx] = a3 + ws[OFF_CST+3];
    }
  }
}

// ---- K2: kq = outb @ Mbf^T + qbk -> kqB frag layout (no LDS, no barriers) --
__global__ __launch_bounds__(256) void k_mkq(float* __restrict__ ws) {
  const u16* outb = (const u16*)(ws + OFF_OUTB);
  const u16* Mbf  = (const u16*)(ws + OFF_MBF);
  u16* kqB = (u16*)(ws + OFF_KQB);
  const float* qbk = ws + OFF_QBK;
  int tid = threadIdx.x, lane = tid & 63, w = tid >> 6;
  const int c4 = lane & 15, q4 = lane >> 4, wr = w >> 1, wc = w & 1;
  const int ti = blockIdx.y, tj = blockIdx.x;
  f32x4 acc[2][2];
#pragma unroll
  for (int i = 0; i < 2; ++i)
#pragma unroll
    for (int j = 0; j < 2; ++j) acc[i][j] = (f32x4){0.f,0.f,0.f,0.f};
  const u16* Ab[2]; const u16* Bb[2];
#pragma unroll
  for (int i = 0; i < 2; ++i)
    Ab[i] = outb + (size_t)(ti*64 + wr*32 + i*16 + c4) * nD + q4*8;
#pragma unroll
  for (int j = 0; j < 2; ++j)
    Bb[j] = Mbf + (size_t)(tj*64 + wc*32 + j*16 + c4) * nD + q4*8;
  for (int kt = 0; kt < 24; ++kt) {
    bf16x8 af[2], bf[2];
#pragma unroll
    for (int i = 0; i < 2; ++i) af[i] = *(const bf16x8*)(Ab[i] + kt*32);
#pragma unroll
    for (int j = 0; j < 2; ++j) bf[j] = *(const bf16x8*)(Bb[j] + kt*32);
#pragma unroll
    for (int i = 0; i < 2; ++i)
#pragma unroll
      for (int j = 0; j < 2; ++j)
        acc[i][j] = __builtin_amdgcn_mfma_f32_16x16x32_bf16(af[i], bf[j], acc[i][j], 0, 0, 0);
  }
#pragma unroll
  for (int i = 0; i < 2; ++i)
#pragma unroll
    for (int j = 0; j < 2; ++j) {
      int n = tj*64 + wc*32 + j*16 + c4;
      float bb = qbk[n];
#pragma unroll
      for (int reg = 0; reg < 4; ++reg) {
        int m = ti*64 + wr*32 + i*16 + q4*4 + reg;
        kqB[(((size_t)(n >> 3)) << 13) + ((size_t)m << 3) + (n & 7)] =
            f2bf(acc[i][j][reg] + bb);
      }
    }
}

// ---- K3: 64r x 512s tile; double-buffered LDS A, 1 barrier/stage -----------
// grid (b 2, rt8 8, l 103); 512 thr = 8 waves, wave 64r x 64c (w = col chunk).
// __launch_bounds__(512,4): cap at 128 unified regs/wave -> 4 waves/SIMD ->
// 2 workgroups/CU co-resident (was 1: 64 AGPR acc + ~76 arch = ~140 regs
// allowed only 3 waves/SIMD -> single 8-wave WG -> latency fully exposed).
__global__ __launch_bounds__(512, 4) void k_attn(
    const float* __restrict__ laws, const u16* __restrict__ kqB,
    const int* __restrict__ mask, float* __restrict__ ws,
    const float* __restrict__ bld, const float* __restrict__ wl1,
    const float* __restrict__ bad, const float* __restrict__ wa1,
    const float* __restrict__ btd, const float* __restrict__ wt1) {
  __shared__ u16 Abuf[2][64 * 200];  // 2 x 64 rows x (192 k + 8 pad) bf16 = 50 KB
  __shared__ f32x4 redS[8][64];      // 8 KB
  const int tid = threadIdx.x, lane = tid & 63, w = tid >> 6;
  const int c4 = lane & 15, q4 = lane >> 4;
  const int b = blockIdx.x, rt8 = blockIdx.y, l = blockIdx.z;

  // A staging: thread -> (row sr 0..63, seg sq 0..7); per stage 6 float4/thread
  // split into two batches of 3 (gA, gB) to keep staging liveness at 12 regs.
  const int sr = tid >> 3, sq = tid & 7;
  const float* Asrc = laws + ((size_t)l * nR + rt8 * 64 + sr) * nD + sq * 4;
  const int awo = sr * 200 + sq * 4;

  // B fragment base: col s = w*64 + ct*16 + c4, k-quad q4
  const u16* Bbase = kqB + ((size_t)q4 * 1024 + (size_t)b * nS + w * 64 + c4) * 8;

  // prologue: load + store stage 0 into Abuf[0]
  float4 g[6];
#pragma unroll
  for (int i = 0; i < 6; ++i) g[i] = *(const float4*)(Asrc + i * 32);

  f32x4 acc[4][4];
#pragma unroll
  for (int rt = 0; rt < 4; ++rt)
#pragma unroll
    for (int ct = 0; ct < 4; ++ct) acc[rt][ct] = (f32x4){0.f,0.f,0.f,0.f};

#pragma unroll
  for (int i = 0; i < 6; ++i) {
    ushort4v u;
    u[0]=f2bf(g[i].x); u[1]=f2bf(g[i].y); u[2]=f2bf(g[i].z); u[3]=f2bf(g[i].w);
    *(ushort4v*)(&Abuf[0][0] + awo + i * 32) = u;
  }
  __syncthreads();

#pragma unroll
  for (int s = 0; s < 4; ++s) {
    const u16* cur = &Abuf[s & 1][0];
    u16* nxt = &Abuf[(s & 1) ^ 1][0];
    float4 gA[3], gB[3];
    if (s < 3) {   // batch A of next stage: hides HBM latency under burst 1
#pragma unroll
      for (int i = 0; i < 3; ++i)
        gA[i] = *(const float4*)(Asrc + (s + 1) * 192 + i * 32);
    }
    // ---- burst 1: kk = 0..2 (no barriers; B loads pipeline freely) ---------
#pragma unroll
    for (int kk = 0; kk < 3; ++kk) {
      const int kt = s * 6 + kk;
      bf16x8 bf[4];
#pragma unroll
      for (int ct = 0; ct < 4; ++ct)
        bf[ct] = *(const bf16x8*)(Bbase + (size_t)kt * 32768 + ct * 128);
#pragma unroll
      for (int rt = 0; rt < 4; ++rt) {
        bf16x8 af = *(const bf16x8*)&cur[(rt * 16 + c4) * 200 + kk * 32 + q4 * 8];
#pragma unroll
        for (int ct = 0; ct < 4; ++ct)
          acc[rt][ct] = __builtin_amdgcn_mfma_f32_16x16x32_bf16(af, bf[ct],
                                                                acc[rt][ct], 0, 0, 0);
      }
    }
    if (s < 3) {
      // write batch A into nxt (other buffer: safe without a barrier),
      // then issue batch B loads (land during burst 2)
#pragma unroll
      for (int i = 0; i < 3; ++i) {
        ushort4v u;
        u[0]=f2bf(gA[i].x); u[1]=f2bf(gA[i].y); u[2]=f2bf(gA[i].z); u[3]=f2bf(gA[i].w);
        *(ushort4v*)(nxt + awo + i * 32) = u;
      }
#pragma unroll
      for (int i = 0; i < 3; ++i)
        gB[i] = *(const float4*)(Asrc + (s + 1) * 192 + (i + 3) * 32);
    }
    // ---- burst 2: kk = 3..5 ------------------------------------------------
#pragma unroll
    for (int kk = 3; kk < 6; ++kk) {
      const int kt = s * 6 + kk;
      bf16x8 bf[4];
#pragma unroll
      for (int ct = 0; ct < 4; ++ct)
        bf[ct] = *(const bf16x8*)(Bbase + (size_t)kt * 32768 + ct * 128);
#pragma unroll
      for (int rt = 0; rt < 4; ++rt) {
        bf16x8 af = *(const bf16x8*)&cur[(rt * 16 + c4) * 200 + kk * 32 + q4 * 8];
#pragma unroll
        for (int ct = 0; ct < 4; ++ct)
          acc[rt][ct] = __builtin_amdgcn_mfma_f32_16x16x32_bf16(af, bf[ct],
                                                                acc[rt][ct], 0, 0, 0);
      }
    }
    if (s < 3) {
#pragma unroll
      for (int i = 0; i < 3; ++i) {
        ushort4v u;
        u[0]=f2bf(gB[i].x); u[1]=f2bf(gB[i].y); u[2]=f2bf(gB[i].z); u[3]=f2bf(gB[i].w);
        *(ushort4v*)(nxt + awo + (i + 3) * 32) = u;
      }
    }
    __syncthreads();   // nxt fully staged + all waves done reading cur
  }

  // ---- per-col scalars: s = w*64 + ct*16 + c4 ------------------------------
  const float* cp  = ws + OFF_C + (size_t)b * nS;
  const float* hlp = ws + OFF_HV + (size_t)b * nS;
  const float* hap = ws + OFF_HV + 1024 + (size_t)b * nS;
  const float* htp = ws + OFF_HV + 2048 + (size_t)b * nS;
  float cc[4], hl[4], ha[4], ht[4], ma[4];
#pragma unroll
  for (int ct = 0; ct < 4; ++ct) {
    int s = w * 64 + ct * 16 + c4;
    cc[ct] = cp[s]; hl[ct] = hlp[s]; ha[ct] = hap[s]; ht[ct] = htp[s];
    ma[ct] = (1.0f - (float)mask[b * nS + s]) * -10000.0f;
  }

  // ---- exp (logits bounded; masked -> underflow 0) + 4 weighted row sums ---
#pragma unroll
  for (int rt = 0; rt < 4; ++rt) {
#pragma unroll
    for (int reg = 0; reg < 4; ++reg) {
      float sse = 0.f, spl = 0.f, spa = 0.f, spt = 0.f;
#pragma unroll
      for (int ct = 0; ct < 4; ++ct) {
        float x = (acc[rt][ct][reg] + cc[ct]) * INV_SQRT_D + ma[ct];
        float e = __expf(x);
        sse += e; spl += e * hl[ct]; spa += e * ha[ct]; spt += e * ht[ct];
      }
#pragma unroll
      for (int o = 1; o < 16; o <<= 1) {
        sse += __shfl_xor(sse, o);
        spl += __shfl_xor(spl, o);
        spa += __shfl_xor(spa, o);
        spt += __shfl_xor(spt, o);
      }
      if (c4 == 0)
        redS[w][rt * 16 + q4 * 4 + reg] = (f32x4){sse, spl, spa, spt};
    }
  }
  __syncthreads();

  // ---- finalize on wave 0: one row per lane --------------------------------
  if (w == 0) {
    int row = lane;
    f32x4 t = (f32x4){0.f,0.f,0.f,0.f};
#pragma unroll
    for (int wc = 0; wc < 8; ++wc) t += redS[wc][row];
    float inv = 1.0f / t[0];
    int r = rt8 * 64 + row;
    float cl = tanhf(t[1] * inv + bld[0]) * wl1[r];
    float ca = tanhf(t[2] * inv + bad[0]) * wa1[r];
    float ctv = tanhf(t[3] * inv + btd[0]) * wt1[r];
#pragma unroll
    for (int o = 1; o < 64; o <<= 1) {
      cl += __shfl_xor(cl, o);
      ca += __shfl_xor(ca, o);
      ctv += __shfl_xor(ctv, o);
    }
    if (lane == 0) {
      float* sums = ws + OFF_SUM;
      atomicAdd(&sums[b * nL + l], cl);
      atomicAdd(&sums[nB * nL + b * nL + l], ca);
      atomicAdd(&sums[2 * nB * nL + b * nL + l], ctv);
    }
  }
}

// ---- K4: finalize heads ----------------------------------------------------
__global__ void k_final(const float* __restrict__ ws, float* __restrict__ out,
                        const float* __restrict__ bl1, const float* __restrict__ ba1,
                        const float* __restrict__ Wa2, const float* __restrict__ ba2,
                        const float* __restrict__ bt1, const float* __restrict__ Wt2,
                        const float* __restrict__ bt2) {
  __shared__ float abl[nB * nL], tbl[nB * nL];
  int t = threadIdx.x;
  const float* sl = ws + OFF_SUM;
  const float* sa = sl + nB * nL;
  const float* st = sa + nB * nL;
  if (t < nB * nL) {
    out[t] = sl[t] + bl1[0];
    abl[t] = tanhf(sa[t] + ba1[0]);
    tbl[t] = tanhf(st[t] + bt1[0]);
  }
  __syncthreads();
  for (int idx = t; idx < nB * 119; idx += 256) {
    int b = idx / 119, j = idx % 119;
    float a = ba2[j];
    for (int ll = 0; ll < nL; ++ll) a += Wa2[j * nL + ll] * abl[b * nL + ll];
    out[nB * nL + idx] = a;
  }
  for (int idx = t; idx < nB * 11; idx += 256) {
    int b = idx / 11, j = idx % 11;
    float a = bt2[j];
    for (int ll = 0; ll < nL; ++ll) a += Wt2[j * nL + ll] * tbl[b * nL + ll];
    out[nB * nL + nB * 119 + idx] = a;
  }
}

extern "C" void kernel_launch(void* const* d_in, const int* in_sizes, int n_in,
                              void* d_out, int out_size, void* d_ws, size_t ws_size,
                              hipStream_t stream) {
  (void)in_sizes; (void)n_in; (void)out_size; (void)ws_size;
  const float* outp = (const float*)d_in[0];
  const int*   mask = (const int*)d_in[1];
  const float* laws = (const float*)d_in[2];
  const float* Wq = (const float*)d_in[3];  const float* bq = (const float*)d_in[4];
  const float* Wk = (const float*)d_in[5];  const float* bk = (const float*)d_in[6];
  const float* Wv = (const float*)d_in[7];  const float* bv = (const float*)d_in[8];
  const float* wld = (const float*)d_in[9];  const float* bld = (const float*)d_in[10];
  const float* wl1 = (const float*)d_in[11]; const float* bl1 = (const float*)d_in[12];
  const float* wad = (const float*)d_in[13]; const float* bad = (const float*)d_in[14];
  const float* wa1 = (const float*)d_in[15]; const float* ba1 = (const float*)d_in[16];
  const float* Wa2 = (const float*)d_in[17]; const float* ba2 = (const float*)d_in[18];
  const float* wtd = (const float*)d_in[19]; const float* btd = (const float*)d_in[20];
  const float* wt1 = (const float*)d_in[21]; const float* bt1 = (const float*)d_in[22];
  const float* Wt2 = (const float*)d_in[23]; const float* bt2 = (const float*)d_in[24];
  float* ws = (float*)d_ws;
  float* fout = (float*)d_out;
  u16* kqB = (u16*)(ws + OFF_KQB);

  // 1) row-dots + consts + zero SUM + pack outp -> bf16
  k_prep<<<385, 256, 0, stream>>>(Wq, Wk, Wv, bq, bk, bv, wld, wad, wtd, outp, ws);
  // 2) M = Wq @ Wk^T (direct-frag MFMA) + chv
  k_mmM_chv<<<400, 256, 0, stream>>>(Wq, Wk, outp, ws);
  // 3) kq = outb @ M^T + qbk -> kqB frag layout
  k_mkq<<<dim3(12, 16), 256, 0, stream>>>(ws);
  // 4) fused scores + full-row softmax + heads (double-buffered, 2 WG/CU)
  k_attn<<<dim3(nB, 8, nL), 512, 0, stream>>>(laws, kqB, mask, ws,
                                              bld, wl1, bad, wa1, btd, wt1);
  // 5) output heads
  k_final<<<1, 256, 0, stream>>>(ws, fout, bl1, ba1, Wa2, ba2, bt1, Wt2, bt2);
}

// Round 5
// 412.707 us; speedup vs baseline: 1.1143x; 1.0338x over previous
//
#include <hip/hip_runtime.h>

static constexpr int nL = 103, nR = 512, nB = 2, nS = 512, nD = 768;
static constexpr float INV_SQRT_D = 0.03608439182435161f; // 1/sqrt(768)

typedef short bf16x8 __attribute__((ext_vector_type(8)));
typedef float f32x4 __attribute__((ext_vector_type(4)));
typedef unsigned short u16;
typedef unsigned short ushort4v __attribute__((ext_vector_type(4)));
typedef unsigned short ushort8v __attribute__((ext_vector_type(8)));

// ws layout (float offsets). Total ~4.16 MiB.
static constexpr size_t OFF_OUTB = 0;                  // 1024x768 bf16 = 393216 fl
static constexpr size_t OFF_MBF  = 393216;             // 768x768 bf16 = 294912 fl
static constexpr size_t OFF_KQB  = 688128;             // 96*1024*8 u16 = 393216 fl
static constexpr size_t OFF_QBK  = 1081344;            // 768 : Wq@bk
static constexpr size_t OFF_WKBQ = OFF_QBK + 768;      // 768 : Wk@bq
static constexpr size_t OFF_WV3  = OFF_WKBQ + 768;     // 3*768 : Wv@{wld,wad,wtd}
static constexpr size_t OFF_CST  = OFF_WV3 + 2304;     // 4
static constexpr size_t OFF_C    = OFF_CST + 4;        // 1024
static constexpr size_t OFF_HV   = OFF_C + 1024;       // 3*1024
static constexpr size_t OFF_SUM  = OFF_HV + 3072;      // 3*nB*nL = 618

__device__ inline float wredsum(float v) {
#pragma unroll
  for (int o = 32; o; o >>= 1) v += __shfl_xor(v, o);
  return v;
}

__device__ inline u16 f2bf(float f) {  // RNE fp32 -> bf16
  unsigned u = __builtin_bit_cast(unsigned, f);
  u += 0x7FFFu + ((u >> 16) & 1u);
  return (u16)(u >> 16);
}

__device__ inline bf16x8 cvt8(float4 a, float4 b) {
  ushort8v u;
  u[0]=f2bf(a.x); u[1]=f2bf(a.y); u[2]=f2bf(a.z); u[3]=f2bf(a.w);
  u[4]=f2bf(b.x); u[5]=f2bf(b.y); u[6]=f2bf(b.z); u[7]=f2bf(b.w);
  return __builtin_bit_cast(bf16x8, u);
}

__device__ inline void st4(u16* dst, float4 g) {
  ushort4v u;
  u[0]=f2bf(g.x); u[1]=f2bf(g.y); u[2]=f2bf(g.z); u[3]=f2bf(g.w);
  *(ushort4v*)dst = u;
}

// ---- K0: row-dots + consts + zero SUM + pack outp->bf16 + M = Wq@Wk^T ------
// (M-part is input-independent of the rest: merged here to overlap with prep
//  and drop one launch. bid: [0,192) dots, 192 consts, [193,385) pack,
//  [385,529) M tiles.)
__global__ __launch_bounds__(256) void k_prep_mm(
    const float* __restrict__ Wq, const float* __restrict__ Wk,
    const float* __restrict__ Wv, const float* __restrict__ bq,
    const float* __restrict__ bk, const float* __restrict__ bv,
    const float* __restrict__ wld, const float* __restrict__ wad,
    const float* __restrict__ wtd, const float* __restrict__ outp,
    float* __restrict__ ws) {
  int tid = threadIdx.x, lane = tid & 63, w = tid >> 6;
  int bid = blockIdx.x;
  if (bid < 192) {
    int row = bid * 4 + w;
    const float* wqr = Wq + (size_t)row * nD;
    const float* wkr = Wk + (size_t)row * nD;
    const float* wvr = Wv + (size_t)row * nD;
    float dq = 0.f, dk = 0.f, d0 = 0.f, d1 = 0.f, d2 = 0.f;
#pragma unroll
    for (int k = 0; k < 3; ++k) {
      int off = lane * 4 + k * 256;
      float4 q4 = *(const float4*)(wqr + off);
      float4 k4 = *(const float4*)(wkr + off);
      float4 v4 = *(const float4*)(wvr + off);
      float4 bk4 = *(const float4*)(bk + off);
      float4 bq4 = *(const float4*)(bq + off);
      float4 l4 = *(const float4*)(wld + off);
      float4 a4 = *(const float4*)(wad + off);
      float4 t4 = *(const float4*)(wtd + off);
      dq += q4.x*bk4.x + q4.y*bk4.y + q4.z*bk4.z + q4.w*bk4.w;
      dk += k4.x*bq4.x + k4.y*bq4.y + k4.z*bq4.z + k4.w*bq4.w;
      d0 += v4.x*l4.x + v4.y*l4.y + v4.z*l4.z + v4.w*l4.w;
      d1 += v4.x*a4.x + v4.y*a4.y + v4.z*a4.z + v4.w*a4.w;
      d2 += v4.x*t4.x + v4.y*t4.y + v4.z*t4.z + v4.w*t4.w;
    }
    dq = wredsum(dq); dk = wredsum(dk);
    d0 = wredsum(d0); d1 = wredsum(d1); d2 = wredsum(d2);
    if (lane == 0) {
      ws[OFF_QBK + row] = dq;
      ws[OFF_WKBQ + row] = dk;
      ws[OFF_WV3 + row] = d0;
      ws[OFF_WV3 + 768 + row] = d1;
      ws[OFF_WV3 + 1536 + row] = d2;
    }
  } else if (bid == 192) {
    if (tid < 64) {
      float c0 = 0.f, c1 = 0.f, c2 = 0.f, c3 = 0.f;
      for (int j = lane; j < nD; j += 64) {
        c0 += bq[j]*bk[j]; c1 += bv[j]*wld[j]; c2 += bv[j]*wad[j]; c3 += bv[j]*wtd[j];
      }
      c0 = wredsum(c0); c1 = wredsum(c1); c2 = wredsum(c2); c3 = wredsum(c3);
      if (lane == 0) {
        ws[OFF_CST+0] = c0; ws[OFF_CST+1] = c1; ws[OFF_CST+2] = c2; ws[OFF_CST+3] = c3;
      }
    }
    for (int i = tid; i < 3 * nB * nL; i += 256) ws[OFF_SUM + i] = 0.f;
  } else if (bid < 385) {
    // pack outp -> outb bf16: 4096 fl per block
    u16* outb = (u16*)(ws + OFF_OUTB);
    size_t e = ((size_t)(bid - 193) * 256 + tid) * 16;
    float4 f0 = *(const float4*)(outp + e);
    float4 f1 = *(const float4*)(outp + e + 4);
    float4 f2 = *(const float4*)(outp + e + 8);
    float4 f3 = *(const float4*)(outp + e + 12);
    *(ushort8v*)(outb + e)     = __builtin_bit_cast(ushort8v, cvt8(f0, f1));
    *(ushort8v*)(outb + e + 8) = __builtin_bit_cast(ushort8v, cvt8(f2, f3));
  } else {
    // M = Wq @ Wk^T (direct-fragment MFMA), 144 tile blocks
    u16* Mbf = (u16*)(ws + OFF_MBF);
    const int mb = bid - 385;
    const int ti = mb / 12, tj = mb % 12;
    const int c4 = lane & 15, q4 = lane >> 4, wr = w >> 1, wc = w & 1;
    f32x4 acc[2][2];
#pragma unroll
    for (int i = 0; i < 2; ++i)
#pragma unroll
      for (int j = 0; j < 2; ++j) acc[i][j] = (f32x4){0.f,0.f,0.f,0.f};
    const float* Ab[2]; const float* Bb[2];
#pragma unroll
    for (int i = 0; i < 2; ++i)
      Ab[i] = Wq + (size_t)(ti*64 + wr*32 + i*16 + c4) * nD + q4*8;
#pragma unroll
    for (int j = 0; j < 2; ++j)
      Bb[j] = Wk + (size_t)(tj*64 + wc*32 + j*16 + c4) * nD + q4*8;
    for (int kt = 0; kt < 24; ++kt) {
      bf16x8 af[2], bf[2];
#pragma unroll
      for (int i = 0; i < 2; ++i)
        af[i] = cvt8(*(const float4*)(Ab[i] + kt*32), *(const float4*)(Ab[i] + kt*32 + 4));
#pragma unroll
      for (int j = 0; j < 2; ++j)
        bf[j] = cvt8(*(const float4*)(Bb[j] + kt*32), *(const float4*)(Bb[j] + kt*32 + 4));
#pragma unroll
      for (int i = 0; i < 2; ++i)
#pragma unroll
        for (int j = 0; j < 2; ++j)
          acc[i][j] = __builtin_amdgcn_mfma_f32_16x16x32_bf16(af[i], bf[j], acc[i][j], 0, 0, 0);
    }
#pragma unroll
    for (int i = 0; i < 2; ++i)
#pragma unroll
      for (int j = 0; j < 2; ++j) {
        int n = tj*64 + wc*32 + j*16 + c4;
#pragma unroll
        for (int reg = 0; reg < 4; ++reg) {
          int m = ti*64 + wr*32 + i*16 + q4*4 + reg;
          Mbf[(size_t)m * nD + n] = f2bf(acc[i][j][reg]);
        }
      }
  }
}

// ---- K1: kq = outb @ Mbf^T + qbk -> kqB frag layout, + fused chv -----------
// bid [0,192): mkq tiles (ti=bid/12, tj=bid%12); [192,448): chv rows.
__global__ __launch_bounds__(256) void k_mkq_chv(
    const float* __restrict__ outp, float* __restrict__ ws) {
  int tid = threadIdx.x, lane = tid & 63, w = tid >> 6;
  int bid = blockIdx.x;
  if (bid < 192) {
    const u16* outb = (const u16*)(ws + OFF_OUTB);
    const u16* Mbf  = (const u16*)(ws + OFF_MBF);
    u16* kqB = (u16*)(ws + OFF_KQB);
    const float* qbk = ws + OFF_QBK;
    const int c4 = lane & 15, q4 = lane >> 4, wr = w >> 1, wc = w & 1;
    const int ti = bid / 12, tj = bid % 12;
    f32x4 acc[2][2];
#pragma unroll
    for (int i = 0; i < 2; ++i)
#pragma unroll
      for (int j = 0; j < 2; ++j) acc[i][j] = (f32x4){0.f,0.f,0.f,0.f};
    const u16* Ab[2]; const u16* Bb[2];
#pragma unroll
    for (int i = 0; i < 2; ++i)
      Ab[i] = outb + (size_t)(ti*64 + wr*32 + i*16 + c4) * nD + q4*8;
#pragma unroll
    for (int j = 0; j < 2; ++j)
      Bb[j] = Mbf + (size_t)(tj*64 + wc*32 + j*16 + c4) * nD + q4*8;
    for (int kt = 0; kt < 24; ++kt) {
      bf16x8 af[2], bf[2];
#pragma unroll
      for (int i = 0; i < 2; ++i) af[i] = *(const bf16x8*)(Ab[i] + kt*32);
#pragma unroll
      for (int j = 0; j < 2; ++j) bf[j] = *(const bf16x8*)(Bb[j] + kt*32);
#pragma unroll
      for (int i = 0; i < 2; ++i)
#pragma unroll
        for (int j = 0; j < 2; ++j)
          acc[i][j] = __builtin_amdgcn_mfma_f32_16x16x32_bf16(af[i], bf[j], acc[i][j], 0, 0, 0);
    }
#pragma unroll
    for (int i = 0; i < 2; ++i)
#pragma unroll
      for (int j = 0; j < 2; ++j) {
        int n = tj*64 + wc*32 + j*16 + c4;
        float bb = qbk[n];
#pragma unroll
        for (int reg = 0; reg < 4; ++reg) {
          int m = ti*64 + wr*32 + i*16 + q4*4 + reg;
          kqB[(((size_t)(n >> 3)) << 13) + ((size_t)m << 3) + (n & 7)] =
              f2bf(acc[i][j][reg] + bb);
        }
      }
  } else {
    // chv: wave per (b,s) row
    int idx = (bid - 192) * 4 + w;
    const float* row = outp + (size_t)idx * nD;
    const float* wkbq = ws + OFF_WKBQ;
    const float* wv0 = ws + OFF_WV3;
    const float* wv1 = ws + OFF_WV3 + 768;
    const float* wv2 = ws + OFF_WV3 + 1536;
    float a0 = 0.f, a1 = 0.f, a2 = 0.f, a3 = 0.f;
#pragma unroll
    for (int k = 0; k < 3; ++k) {
      int off = lane * 4 + k * 256;
      float4 o4 = *(const float4*)(row + off);
      float4 k4 = *(const float4*)(wkbq + off);
      float4 l4 = *(const float4*)(wv0 + off);
      float4 c4v = *(const float4*)(wv1 + off);
      float4 t4 = *(const float4*)(wv2 + off);
      a0 += o4.x*k4.x + o4.y*k4.y + o4.z*k4.z + o4.w*k4.w;
      a1 += o4.x*l4.x + o4.y*l4.y + o4.z*l4.z + o4.w*l4.w;
      a2 += o4.x*c4v.x + o4.y*c4v.y + o4.z*c4v.z + o4.w*c4v.w;
      a3 += o4.x*t4.x + o4.y*t4.y + o4.z*t4.z + o4.w*t4.w;
    }
    a0 = wredsum(a0); a1 = wredsum(a1); a2 = wredsum(a2); a3 = wredsum(a3);
    if (lane == 0) {
      ws[OFF_C + idx]         = a0 + ws[OFF_CST+0];
      ws[OFF_HV + idx]        = a1 + ws[OFF_CST+1];
      ws[OFF_HV + 1024 + idx] = a2 + ws[OFF_CST+2];
      ws[OFF_HV + 2048 + idx] = a3 + ws[OFF_CST+3];
    }
  }
}

// ---- K2: 64r x 512s tile; double-buffered LDS A, 1 barrier/stage -----------
// grid (b 2, rt8 8, l 103); 512 thr = 8 waves, wave 64r x 64c (w = col chunk).
// __launch_bounds__(512,4): 128 unified regs/wave -> 2 WGs/CU. Staging is
// 3 batches of 2 float4 (peak 8 VGPR; the previous 2x3 scheme peaked at 12
// and spilled ~8 regs -> 26.5 MB/dispatch scratch WRITE_SIZE).
__global__ __launch_bounds__(512, 4) void k_attn(
    const float* __restrict__ laws, const u16* __restrict__ kqB,
    const int* __restrict__ mask, float* __restrict__ ws,
    const float* __restrict__ bld, const float* __restrict__ wl1,
    const float* __restrict__ bad, const float* __restrict__ wa1,
    const float* __restrict__ btd, const float* __restrict__ wt1) {
  __shared__ u16 Abuf[2][64 * 200];  // 2 x 64 rows x (192 k + 8 pad) bf16 = 50 KB
  __shared__ f32x4 redS[8][64];      // 8 KB
  const int tid = threadIdx.x, lane = tid & 63, w = tid >> 6;
  const int c4 = lane & 15, q4 = lane >> 4;
  const int b = blockIdx.x, rt8 = blockIdx.y, l = blockIdx.z;

  // A staging: thread -> (row sr 0..63, seg sq 0..7); per stage 6 float4/thread
  const int sr = tid >> 3, sq = tid & 7;
  const float* Asrc = laws + ((size_t)l * nR + rt8 * 64 + sr) * nD + sq * 4;
  const int awo = sr * 200 + sq * 4;

  // B fragment base: col s = w*64 + ct*16 + c4, k-quad q4
  const u16* Bbase = kqB + ((size_t)q4 * 1024 + (size_t)b * nS + w * 64 + c4) * 8;

  f32x4 acc[4][4];
#pragma unroll
  for (int rt = 0; rt < 4; ++rt)
#pragma unroll
    for (int ct = 0; ct < 4; ++ct) acc[rt][ct] = (f32x4){0.f,0.f,0.f,0.f};

  // prologue: load + store stage 0 into Abuf[0] (2-at-a-time, low liveness)
#pragma unroll
  for (int j = 0; j < 3; ++j) {
    float4 p0 = *(const float4*)(Asrc + (2*j) * 32);
    float4 p1 = *(const float4*)(Asrc + (2*j+1) * 32);
    st4(&Abuf[0][0] + awo + (2*j) * 32, p0);
    st4(&Abuf[0][0] + awo + (2*j+1) * 32, p1);
  }
  __syncthreads();

  // per-kk compute: 4 B frags + 4 A frags + 16 MFMA
#define COMPUTE_KK(CUR, KT, KK)                                               \
  do {                                                                        \
    bf16x8 bf0 = *(const bf16x8*)(Bbase + (size_t)(KT) * 32768 + 0 * 128);    \
    bf16x8 bf1 = *(const bf16x8*)(Bbase + (size_t)(KT) * 32768 + 1 * 128);    \
    bf16x8 bf2 = *(const bf16x8*)(Bbase + (size_t)(KT) * 32768 + 2 * 128);    \
    bf16x8 bf3 = *(const bf16x8*)(Bbase + (size_t)(KT) * 32768 + 3 * 128);    \
    _Pragma("unroll")                                                         \
    for (int rt = 0; rt < 4; ++rt) {                                          \
      bf16x8 af = *(const bf16x8*)&(CUR)[(rt * 16 + c4) * 200 + (KK) * 32 + q4 * 8]; \
      acc[rt][0] = __builtin_amdgcn_mfma_f32_16x16x32_bf16(af, bf0, acc[rt][0], 0, 0, 0); \
      acc[rt][1] = __builtin_amdgcn_mfma_f32_16x16x32_bf16(af, bf1, acc[rt][1], 0, 0, 0); \
      acc[rt][2] = __builtin_amdgcn_mfma_f32_16x16x32_bf16(af, bf2, acc[rt][2], 0, 0, 0); \
      acc[rt][3] = __builtin_amdgcn_mfma_f32_16x16x32_bf16(af, bf3, acc[rt][3], 0, 0, 0); \
    }                                                                         \
  } while (0)

#pragma unroll
  for (int s = 0; s < 4; ++s) {
    const u16* cur = &Abuf[s & 1][0];
    u16* nxt = &Abuf[(s & 1) ^ 1][0];
    float4 g0, g1;
    // batch 0 loads: whole burst(0,1) + write distance to cover HBM latency
    if (s < 3) {
      g0 = *(const float4*)(Asrc + (s + 1) * 192 + 0 * 32);
      g1 = *(const float4*)(Asrc + (s + 1) * 192 + 1 * 32);
    }
    COMPUTE_KK(cur, s * 6 + 0, 0);
    COMPUTE_KK(cur, s * 6 + 1, 1);
    if (s < 3) {   // write batch 0 into nxt (safe: other buffer), load batch 1
      st4(nxt + awo + 0 * 32, g0);
      st4(nxt + awo + 1 * 32, g1);
      g0 = *(const float4*)(Asrc + (s + 1) * 192 + 2 * 32);
      g1 = *(const float4*)(Asrc + (s + 1) * 192 + 3 * 32);
    }
    COMPUTE_KK(cur, s * 6 + 2, 2);
    COMPUTE_KK(cur, s * 6 + 3, 3);
    if (s < 3) {   // write batch 1, load batch 2
      st4(nxt + awo + 2 * 32, g0);
      st4(nxt + awo + 3 * 32, g1);
      g0 = *(const float4*)(Asrc + (s + 1) * 192 + 4 * 32);
      g1 = *(const float4*)(Asrc + (s + 1) * 192 + 5 * 32);
    }
    COMPUTE_KK(cur, s * 6 + 4, 4);
    COMPUTE_KK(cur, s * 6 + 5, 5);
    if (s < 3) {   // write batch 2
      st4(nxt + awo + 4 * 32, g0);
      st4(nxt + awo + 5 * 32, g1);
    }
    __syncthreads();   // nxt fully staged + all waves done reading cur
  }
#undef COMPUTE_KK

  // ---- per-col scalars: s = w*64 + ct*16 + c4 ------------------------------
  const float* cp  = ws + OFF_C + (size_t)b * nS;
  const float* hlp = ws + OFF_HV + (size_t)b * nS;
  const float* hap = ws + OFF_HV + 1024 + (size_t)b * nS;
  const float* htp = ws + OFF_HV + 2048 + (size_t)b * nS;
  float cc[4], hl[4], ha[4], ht[4], ma[4];
#pragma unroll
  for (int ct = 0; ct < 4; ++ct) {
    int s = w * 64 + ct * 16 + c4;
    cc[ct] = cp[s]; hl[ct] = hlp[s]; ha[ct] = hap[s]; ht[ct] = htp[s];
    ma[ct] = (1.0f - (float)mask[b * nS + s]) * -10000.0f;
  }

  // ---- exp (logits bounded; masked -> underflow 0) + 4 weighted row sums ---
#pragma unroll
  for (int rt = 0; rt < 4; ++rt) {
#pragma unroll
    for (int reg = 0; reg < 4; ++reg) {
      float sse = 0.f, spl = 0.f, spa = 0.f, spt = 0.f;
#pragma unroll
      for (int ct = 0; ct < 4; ++ct) {
        float x = (acc[rt][ct][reg] + cc[ct]) * INV_SQRT_D + ma[ct];
        float e = __expf(x);
        sse += e; spl += e * hl[ct]; spa += e * ha[ct]; spt += e * ht[ct];
      }
#pragma unroll
      for (int o = 1; o < 16; o <<= 1) {
        sse += __shfl_xor(sse, o);
        spl += __shfl_xor(spl, o);
        spa += __shfl_xor(spa, o);
        spt += __shfl_xor(spt, o);
      }
      if (c4 == 0)
        redS[w][rt * 16 + q4 * 4 + reg] = (f32x4){sse, spl, spa, spt};
    }
  }
  __syncthreads();

  // ---- finalize on wave 0: one row per lane --------------------------------
  if (w == 0) {
    int row = lane;
    f32x4 t = (f32x4){0.f,0.f,0.f,0.f};
#pragma unroll
    for (int wc = 0; wc < 8; ++wc) t += redS[wc][row];
    float inv = 1.0f / t[0];
    int r = rt8 * 64 + row;
    float cl = tanhf(t[1] * inv + bld[0]) * wl1[r];
    float ca = tanhf(t[2] * inv + bad[0]) * wa1[r];
    float ctv = tanhf(t[3] * inv + btd[0]) * wt1[r];
#pragma unroll
    for (int o = 1; o < 64; o <<= 1) {
      cl += __shfl_xor(cl, o);
      ca += __shfl_xor(ca, o);
      ctv += __shfl_xor(ctv, o);
    }
    if (lane == 0) {
      float* sums = ws + OFF_SUM;
      atomicAdd(&sums[b * nL + l], cl);
      atomicAdd(&sums[nB * nL + b * nL + l], ca);
      atomicAdd(&sums[2 * nB * nL + b * nL + l], ctv);
    }
  }
}

// ---- K3: finalize heads ----------------------------------------------------
__global__ void k_final(const float* __restrict__ ws, float* __restrict__ out,
                        const float* __restrict__ bl1, const float* __restrict__ ba1,
                        const float* __restrict__ Wa2, const float* __restrict__ ba2,
                        const float* __restrict__ bt1, const float* __restrict__ Wt2,
                        const float* __restrict__ bt2) {
  __shared__ float abl[nB * nL], tbl[nB * nL];
  int t = threadIdx.x;
  const float* sl = ws + OFF_SUM;
  const float* sa = sl + nB * nL;
  const float* st = sa + nB * nL;
  if (t < nB * nL) {
    out[t] = sl[t] + bl1[0];
    abl[t] = tanhf(sa[t] + ba1[0]);
    tbl[t] = tanhf(st[t] + bt1[0]);
  }
  __syncthreads();
  for (int idx = t; idx < nB * 119; idx += 256) {
    int b = idx / 119, j = idx % 119;
    float a = ba2[j];
    for (int ll = 0; ll < nL; ++ll) a += Wa2[j * nL + ll] * abl[b * nL + ll];
    out[nB * nL + idx] = a;
  }
  for (int idx = t; idx < nB * 11; idx += 256) {
    int b = idx / 11, j = idx % 11;
    float a = bt2[j];
    for (int ll = 0; ll < nL; ++ll) a += Wt2[j * nL + ll] * tbl[b * nL + ll];
    out[nB * nL + nB * 119 + idx] = a;
  }
}

extern "C" void kernel_launch(void* const* d_in, const int* in_sizes, int n_in,
                              void* d_out, int out_size, void* d_ws, size_t ws_size,
                              hipStream_t stream) {
  (void)in_sizes; (void)n_in; (void)out_size; (void)ws_size;
  const float* outp = (const float*)d_in[0];
  const int*   mask = (const int*)d_in[1];
  const float* laws = (const float*)d_in[2];
  const float* Wq = (const float*)d_in[3];  const float* bq = (const float*)d_in[4];
  const float* Wk = (const float*)d_in[5];  const float* bk = (const float*)d_in[6];
  const float* Wv = (const float*)d_in[7];  const float* bv = (const float*)d_in[8];
  const float* wld = (const float*)d_in[9];  const float* bld = (const float*)d_in[10];
  const float* wl1 = (const float*)d_in[11]; const float* bl1 = (const float*)d_in[12];
  const float* wad = (const float*)d_in[13]; const float* bad = (const float*)d_in[14];
  const float* wa1 = (const float*)d_in[15]; const float* ba1 = (const float*)d_in[16];
  const float* Wa2 = (const float*)d_in[17]; const float* ba2 = (const float*)d_in[18];
  const float* wtd = (const float*)d_in[19]; const float* btd = (const float*)d_in[20];
  const float* wt1 = (const float*)d_in[21]; const float* bt1 = (const float*)d_in[22];
  const float* Wt2 = (const float*)d_in[23]; const float* bt2 = (const float*)d_in[24];
  float* ws = (float*)d_ws;
  float* fout = (float*)d_out;
  u16* kqB = (u16*)(ws + OFF_KQB);

  // 1) row-dots + consts + zero SUM + pack outp -> bf16 + M = Wq@Wk^T
  k_prep_mm<<<529, 256, 0, stream>>>(Wq, Wk, Wv, bq, bk, bv, wld, wad, wtd, outp, ws);
  // 2) kq = outb @ M^T + qbk -> kqB frag layout, + chv
  k_mkq_chv<<<448, 256, 0, stream>>>(outp, ws);
  // 3) fused scores + full-row softmax + heads (double-buffered, 2 WG/CU)
  k_attn<<<dim3(nB, 8, nL), 512, 0, stream>>>(laws, kqB, mask, ws,
                                              bld, wl1, bad, wa1, btd, wt1);
  // 4) output heads
  k_final<<<1, 256, 0, stream>>>(ws, fout, bl1, ba1, Wa2, ba2, bt1, Wt2, bt2);
}